// Round 1
// baseline (13.064 us; speedup 1.0000x reference)
//
#include <hip/hip_runtime.h>

// BagOfWords: out[b][v] = count of token v in docs[b][:] / SEQ
// docs: int32 [256, 2048], out: float32 [256, 32000]

#define VOCAB 32000
#define BATCH 256
#define SEQ   2048
#define NCHUNK 4
#define CHUNK (VOCAB / NCHUNK)   // 8000 bins -> 32 KB LDS per workgroup
#define BLK   256

__global__ __launch_bounds__(BLK) void bow_hist_kernel(
    const int* __restrict__ docs, float* __restrict__ out) {
    __shared__ unsigned int bins[CHUNK];

    const int wg   = blockIdx.x;       // 0 .. BATCH*NCHUNK-1
    const int b    = wg >> 2;          // row index
    const int c    = wg & (NCHUNK - 1);
    const int base = c * CHUNK;
    const int tid  = threadIdx.x;

    // 1) zero the LDS histogram chunk
    #pragma unroll
    for (int i = tid; i < CHUNK; i += BLK) bins[i] = 0u;
    __syncthreads();

    // 2) scan this row's tokens (vectorized int4 loads: SEQ/4 = 512 int4)
    const int4* row4 = reinterpret_cast<const int4*>(docs + (size_t)b * SEQ);
    #pragma unroll
    for (int it = 0; it < SEQ / 4 / BLK; ++it) {   // 2 iters
        int4 t = row4[it * BLK + tid];
        int r0 = t.x - base, r1 = t.y - base, r2 = t.z - base, r3 = t.w - base;
        if ((unsigned)r0 < (unsigned)CHUNK) atomicAdd(&bins[r0], 1u);
        if ((unsigned)r1 < (unsigned)CHUNK) atomicAdd(&bins[r1], 1u);
        if ((unsigned)r2 < (unsigned)CHUNK) atomicAdd(&bins[r2], 1u);
        if ((unsigned)r3 < (unsigned)CHUNK) atomicAdd(&bins[r3], 1u);
    }
    __syncthreads();

    // 3) stream the chunk out, normalized; coalesced float4 stores
    float* orow = out + (size_t)b * VOCAB + base;
    const float inv = 1.0f / (float)SEQ;   // exact power of two
    #pragma unroll
    for (int i = tid; i < CHUNK / 4; i += BLK) {   // 2000 float4 per WG
        float4 v;
        v.x = (float)bins[i * 4 + 0] * inv;
        v.y = (float)bins[i * 4 + 1] * inv;
        v.z = (float)bins[i * 4 + 2] * inv;
        v.w = (float)bins[i * 4 + 3] * inv;
        reinterpret_cast<float4*>(orow)[i] = v;
    }
}

extern "C" void kernel_launch(void* const* d_in, const int* in_sizes, int n_in,
                              void* d_out, int out_size, void* d_ws, size_t ws_size,
                              hipStream_t stream) {
    const int* docs = (const int*)d_in[0];
    float* out = (float*)d_out;
    dim3 grid(BATCH * NCHUNK);
    dim3 block(BLK);
    bow_hist_kernel<<<grid, block, 0, stream>>>(docs, out);
}